// Round 7
// baseline (108.731 us; speedup 1.0000x reference)
//
#include <hip/hip_runtime.h>
#include <stdint.h>

#define NPTS 8192
#define DIM  256
#define CAP  32768       // global edge capacity (expected ~1100)
#define LDSE 8192        // in-LDS edge capacity for the UF kernel
#define IBCAP 256        // per-block in-band candidate capacity
#define BAND 2.0e-3f     // > bound ~9.8e-4 on |sim_exact - sim_fp16h| (unit rows)

typedef _Float16 f16x8  __attribute__((ext_vector_type(8)));
typedef float    f32x16 __attribute__((ext_vector_type(16)));

// ws layout: [0..64)  ctr: ctr[0]=edge count
//            [64..)   edges (CAP u32)
//            [1M..)   Vh    (4 MB fp16)

// ---------------------------------------------------------------------------
// Convert V fp32 -> fp16 high half (RTNE); block 0 zeroes the counter.
// ---------------------------------------------------------------------------
__global__ __launch_bounds__(256) void convert_kernel(
        const float* __restrict__ V, _Float16* __restrict__ Vh,
        unsigned* __restrict__ ctr) {
    if (blockIdx.x == 0 && threadIdx.x == 0) { ctr[0] = 0u; ctr[1] = 0u; }
    size_t t = (size_t)blockIdx.x * 256 + threadIdx.x;   // 262144 threads
    const float4* src = reinterpret_cast<const float4*>(V) + t * 2;
    float4 v0 = src[0], v1 = src[1];
    f16x8 h;
    h[0] = (_Float16)v0.x; h[1] = (_Float16)v0.y;
    h[2] = (_Float16)v0.z; h[3] = (_Float16)v0.w;
    h[4] = (_Float16)v1.x; h[5] = (_Float16)v1.y;
    h[6] = (_Float16)v1.z; h[7] = (_Float16)v1.w;
    *reinterpret_cast<f16x8*>(Vh + t * 8) = h;
}

__global__ void init_count(unsigned* ctr) {
    if (threadIdx.x == 0) { ctr[0] = 0u; ctr[1] = 0u; }
}

// ---------------------------------------------------------------------------
__device__ __forceinline__ void gload_lds16(const void* g, void* l) {
    __builtin_amdgcn_global_load_lds(
        (const __attribute__((address_space(1))) void*)g,
        (__attribute__((address_space(3))) void*)l, 16, 0, 0);
}

// ---------------------------------------------------------------------------
// h-only MFMA edge kernel v2.
// 256x256 block tile, 512 threads = 8 waves (2 x 4), wave tile 128x64
// (4x2 of 32x32), v_mfma_f32_32x32x16_f16, KC=64, double-buffered LDS
// (2 x 64 KB) staged via global_load_lds with pre-swizzled source.
// Reuse: (4+2) fragment reads per 8 MFMAs = 0.75 KB LDS per MFMA -> LDS at
// 75% of its ceiling when the MFMA pipe is saturated (was 1.0 -> LDS-bound).
// Stage(next) is issued BEFORE compute(cur); the __syncthreads at phase end
// performs the vmcnt drain, so HBM/L3 latency hides under ~2048 MFMA cycles.
// Classification: sim >= thr+BAND -> sure edge; |sim-thr| < BAND -> deferred
// to an in-block LDS list, re-resolved exactly in fp64 after acc regs die.
// C/D layout (m74/m101): col = lane&31, row = (reg&3)+8*(reg>>2)+4*(lane>>5);
// dual-operand same-k-map convention verified absmax=0 in rounds 3/5/6.
// ---------------------------------------------------------------------------
__global__ __launch_bounds__(512, 2) void edge_mfma(
        const _Float16* __restrict__ Vh,
        const float* __restrict__ V,
        const float* __restrict__ thr_p,
        unsigned* __restrict__ ctr,
        unsigned* __restrict__ edges) {
    // decode triangular tile index over 32 row-tiles: off(b) = 32b - b(b-1)/2
    int t = blockIdx.x;
    int bi = (int)(32.5f - sqrtf(32.5f * 32.5f - 2.0f * (float)t));
    while (bi * 32 - (bi * (bi - 1)) / 2 > t) --bi;
    while ((bi + 1) * 32 - ((bi + 1) * bi) / 2 <= t) ++bi;
    int bj = bi + (t - (bi * 32 - (bi * (bi - 1)) / 2));

    __shared__ _Float16 L[2][32768];           // [buf][A(16K halves)|B(16K halves)]
    __shared__ unsigned ibl[IBCAP];            // in-band candidate keys
    __shared__ unsigned ibn;

    const float thr = thr_p[0];
    const float hi = thr + BAND, lo = thr - BAND;
    const int tid  = threadIdx.x;
    const int lane = tid & 63;
    const int wid  = tid >> 6;
    const int wr = wid >> 2, wc = wid & 3;     // 2 x 4 wave grid
    const int i0 = bi * 256, j0 = bj * 256;

    if (tid == 0) ibn = 0u;

    f32x16 acc[4][2];
#pragma unroll
    for (int a = 0; a < 4; ++a)
#pragma unroll
        for (int b = 0; b < 2; ++b) acc[a][b] = 0.0f;

    const int row_l = lane >> 3;               // 0..7 within 8-row instance
    const int bphys = lane & 7;                // physical 16B block
    const int l31 = lane & 31, g = lane >> 5, l7 = lane & 7;
    // per-lane pre-swizzled global column block (logical = phys ^ row&7)
    const int cblk = bphys ^ row_l;

    // ---- stage one 64 KB buffer: 64 instances of 1 KB, 8 per wave ----
    auto STAGE = [&](int buf, int kc) {
#pragma unroll
        for (int q = 0; q < 8; ++q) {
            const int qq  = wid * 8 + q;       // 0..63
            const int arr = qq >> 5;           // 0:A 1:B
            const int ins = qq & 31;           // 0..31 (8 rows each)
            const int grow = (arr ? j0 : i0) + ins * 8 + row_l;
            gload_lds16(Vh + ((size_t)grow * DIM + kc + cblk * 8),
                        &L[buf][arr * 16384 + ins * 512]);
        }
    };

    // ---- compute one KC=64 tile from buf ----
    auto COMPUTE = [&](int buf) {
#pragma unroll
        for (int s = 0; s < 4; ++s) {
            const int xa = (((s * 2 + g) ^ l7) << 3);   // halves offset in row
            f16x8 af[4], bf[2];
#pragma unroll
            for (int a = 0; a < 4; ++a)
                af[a] = *(const f16x8*)&L[buf][(wr * 128 + a * 32 + l31) * 64 + xa];
#pragma unroll
            for (int b = 0; b < 2; ++b)
                bf[b] = *(const f16x8*)&L[buf][16384 + (wc * 64 + b * 32 + l31) * 64 + xa];
#pragma unroll
            for (int a = 0; a < 4; ++a)
#pragma unroll
                for (int b = 0; b < 2; ++b)
                    acc[a][b] = __builtin_amdgcn_mfma_f32_32x32x16_f16(
                        af[a], bf[b], acc[a][b], 0, 0, 0);
        }
    };

    STAGE(0, 0);
    __syncthreads();
    STAGE(1, 64);  COMPUTE(0); __syncthreads();
    STAGE(0, 128); COMPUTE(1); __syncthreads();
    STAGE(1, 192); COMPUTE(0); __syncthreads();
    COMPUTE(1);
    __syncthreads();

    // ---- epilogue pass 1: classify; sure edges emit, in-band defer ----
#pragma unroll
    for (int a = 0; a < 4; ++a)
#pragma unroll
        for (int b = 0; b < 2; ++b)
#pragma unroll
            for (int reg = 0; reg < 16; ++reg) {
                float sim = acc[a][b][reg];
                int rr = (reg & 3) + 8 * (reg >> 2) + 4 * g;
                int i = i0 + wr * 128 + a * 32 + rr;
                int j = j0 + wc * 64 + b * 32 + l31;
                if (j > i && sim >= lo) {
                    unsigned key = ((unsigned)i << 13) | (unsigned)j;
                    if (sim >= hi) {
                        unsigned p = atomicAdd(&ctr[0], 1u);
                        if (p < CAP) edges[p] = key;
                    } else {
                        unsigned p = atomicAdd(&ibn, 1u);
                        if (p < IBCAP) ibl[p] = key;
                    }
                }
            }
    __syncthreads();

    // ---- epilogue pass 2: exact fp64 re-resolution (acc regs dead) ----
    unsigned nib = ibn; if (nib > IBCAP) nib = IBCAP;
    const double thrd = (double)thr;
    for (unsigned q = tid; q < nib; q += 512) {
        unsigned key = ibl[q];
        int i = (int)(key >> 13), j = (int)(key & 8191u);
        const float4* a4 = reinterpret_cast<const float4*>(V + (size_t)i * DIM);
        const float4* b4 = reinterpret_cast<const float4*>(V + (size_t)j * DIM);
        double s = 0.0;
#pragma unroll 4
        for (int k = 0; k < DIM / 4; ++k) {
            float4 x = a4[k], y = b4[k];
            s += (double)x.x * y.x + (double)x.y * y.y
               + (double)x.z * y.z + (double)x.w * y.w;
        }
        if (s >= thrd) {
            unsigned p = atomicAdd(&ctr[0], 1u);
            if (p < CAP) edges[p] = key;
        }
    }
}

// ---------------------------------------------------------------------------
// fp32 fallback (exact path, no band) if ws is too small for Vh.
// ---------------------------------------------------------------------------
__global__ __launch_bounds__(256) void edge_kernel(
        const float* __restrict__ V,
        const float* __restrict__ thr_p,
        unsigned*    __restrict__ ctr,
        unsigned*    __restrict__ edges) {
    const int bi = blockIdx.y, bj = blockIdx.x;
    if (bj < bi) return;

    __shared__ float As[128 * 32];
    __shared__ float Bs[128 * 32];

    const float thr = thr_p[0];
    const int tid = threadIdx.x;
    const int tx = tid & 15, ty = tid >> 4;
    const int i0 = bi * 128, j0 = bj * 128;

    float acc[8][8];
#pragma unroll
    for (int r = 0; r < 8; ++r)
#pragma unroll
        for (int c = 0; c < 8; ++c) acc[r][c] = 0.f;

    const int srow = tid >> 3, sq = tid & 7;

    for (int kc = 0; kc < DIM; kc += 32) {
#pragma unroll
        for (int p = 0; p < 4; ++p) {
            int row = srow + 32 * p;
            float4 va = *reinterpret_cast<const float4*>(
                &V[(size_t)(i0 + row) * DIM + kc + sq * 4]);
            float4 vb = *reinterpret_cast<const float4*>(
                &V[(size_t)(j0 + row) * DIM + kc + sq * 4]);
            int w = row * 32 + ((sq ^ ((row >> 3) & 7)) << 2);
            *reinterpret_cast<float4*>(&As[w]) = va;
            *reinterpret_cast<float4*>(&Bs[w]) = vb;
        }
        __syncthreads();
#pragma unroll
        for (int k4 = 0; k4 < 8; ++k4) {
            const float* pA = &As[(ty * 8) * 32 + ((k4 ^ (ty & 7)) << 2)];
            const float* pB = &Bs[(tx * 8) * 32 + ((k4 ^ (tx & 7)) << 2)];
            float4 a[8], b[8];
#pragma unroll
            for (int r = 0; r < 8; ++r)
                a[r] = *reinterpret_cast<const float4*>(&pA[r * 32]);
#pragma unroll
            for (int c = 0; c < 8; ++c)
                b[c] = *reinterpret_cast<const float4*>(&pB[c * 32]);
#pragma unroll
            for (int r = 0; r < 8; ++r)
#pragma unroll
                for (int c = 0; c < 8; ++c) {
                    acc[r][c] = fmaf(a[r].x, b[c].x, acc[r][c]);
                    acc[r][c] = fmaf(a[r].y, b[c].y, acc[r][c]);
                    acc[r][c] = fmaf(a[r].z, b[c].z, acc[r][c]);
                    acc[r][c] = fmaf(a[r].w, b[c].w, acc[r][c]);
                }
        }
        __syncthreads();
    }
#pragma unroll
    for (int r = 0; r < 8; ++r)
#pragma unroll
        for (int c = 0; c < 8; ++c) {
            int i = i0 + ty * 8 + r;
            int j = j0 + tx * 8 + c;
            if (j > i && acc[r][c] >= thr) {
                unsigned p = atomicAdd(&ctr[0], 1u);
                if (p < CAP) edges[p] = ((unsigned)i << 13) | (unsigned)j;
            }
        }
}

// ---------------------------------------------------------------------------
// UF kernel (one block, 1024 threads): parallel winner-rounds exact replay
// of the sequential merge, then parallel root write-out.
//
// Winner-rounds correctness: per round each live edge e computes its current
// roots (ri,rj) and atomicMin's its packed key (= sequential order index)
// into S[ri], S[rj].  e applies iff it holds both slots.  (a) Every live
// edge f<e is then root-disjoint from e; disjoint unions commute, so e's
// state restricted to its roots equals its sequential state -> par[rj]=ri
// is the exact sequential effect.  (b) Winner root-sets are pairwise
// disjoint (shared root => equal slot value => equal key; keys unique), so
// parallel application + root-preserving compression is race-free, and
// concurrent phase-B finds cannot produce a false win.  (c) The globally
// smallest live key always wins -> >=1 retire/round.
// Ping-pong slot arrays: phase B clears the OTHER array, so each round has
// exactly 2 barriers (the second fused into __syncthreads_count liveness).
// ---------------------------------------------------------------------------
__global__ __launch_bounds__(1024) void uf_kernel(
        const unsigned* __restrict__ ctr,
        const unsigned* __restrict__ edges,
        int* __restrict__ out) {
    __shared__ int      par[NPTS];        // 32 KB
    __shared__ unsigned slotA[NPTS];      // 32 KB
    __shared__ unsigned slotB[NPTS];      // 32 KB
    __shared__ unsigned sedge[LDSE];      // 32 KB

    const int tid = threadIdx.x;

    unsigned EC = ctr[0]; if (EC > LDSE) EC = LDSE;

    for (int t = tid; t < NPTS; t += 1024) {
        par[t] = t; slotA[t] = 0xFFFFFFFFu; slotB[t] = 0xFFFFFFFFu;
    }
    for (unsigned e = tid; e < EC; e += 1024) sedge[e] = edges[e];
    __syncthreads();

    volatile int* vpar = par;

    for (int round = 0;; ++round) {
        unsigned* S = (round & 1) ? slotB : slotA;
        unsigned* T = (round & 1) ? slotA : slotB;

        // Phase A: finds against round-start state + slot bids
        for (unsigned e = tid; e < EC; e += 1024) {
            unsigned key = sedge[e];
            if (key & 0x80000000u) continue;
            int ri = (int)(key >> 13), rj = (int)(key & 8191u);
            int p;
            while ((p = vpar[ri]) != ri) ri = p;
            while ((p = vpar[rj]) != rj) rj = p;
            atomicMin(&S[ri], key);
            atomicMin(&S[rj], key);
        }
        __syncthreads();

        // Phase B: winners apply; clear other slot array; track liveness
        int mylive = 0;
        for (unsigned e = tid; e < EC; e += 1024) {
            unsigned key = sedge[e];
            if (key & 0x80000000u) continue;
            int i = (int)(key >> 13), j = (int)(key & 8191u);
            int ri = i, rj = j, p;
            while ((p = vpar[ri]) != ri) ri = p;
            while ((p = vpar[rj]) != rj) rj = p;
            if (S[ri] == key && S[rj] == key) {
                if (ri != rj) { par[rj] = ri; par[i] = ri; par[j] = ri; }
                sedge[e] = key | 0x80000000u;
            } else {
                mylive = 1;
            }
        }
        for (int t = tid; t < NPTS; t += 1024) T[t] = 0xFFFFFFFFu;
        if (__syncthreads_count(mylive) == 0) break;
    }

    // ---- root write-out ----
    for (int t = tid; t < NPTS; t += 1024) {
        int r = t, p;
        while ((p = par[r]) != r) r = p;
        out[t] = r;
    }
}

extern "C" void kernel_launch(void* const* d_in, const int* in_sizes, int n_in,
                              void* d_out, int out_size, void* d_ws, size_t ws_size,
                              hipStream_t stream) {
    const float* V     = (const float*)d_in[0];
    const float* thr_p = (const float*)d_in[1];
    // d_in[2] (batch_size) provably does not affect the result.

    unsigned* ctr   = (unsigned*)d_ws;
    unsigned* edges = (unsigned*)((char*)d_ws + 64);
    int*      out   = (int*)d_out;

    const size_t vhOff = 1u << 20;
    const size_t vN    = (size_t)NPTS * DIM;
    const size_t need  = vhOff + vN * sizeof(_Float16) + 65536;

    if (ws_size >= need) {
        _Float16* Vh = (_Float16*)((char*)d_ws + vhOff);
        hipLaunchKernelGGL(convert_kernel, dim3(1024), dim3(256), 0, stream,
                           V, Vh, ctr);
        hipLaunchKernelGGL(edge_mfma, dim3(528), dim3(512), 0, stream,
                           Vh, V, thr_p, ctr, edges);
    } else {
        hipLaunchKernelGGL(init_count, dim3(1), dim3(64), 0, stream, ctr);
        hipLaunchKernelGGL(edge_kernel, dim3(64, 64), dim3(256), 0, stream,
                           V, thr_p, ctr, edges);
    }
    hipLaunchKernelGGL(uf_kernel, dim3(1), dim3(1024), 0, stream,
                       ctr, edges, out);
}

// Round 8
// 103.672 us; speedup vs baseline: 1.0488x; 1.0488x over previous
//
#include <hip/hip_runtime.h>
#include <stdint.h>

#define NPTS 8192
#define DIM  256
#define CAP  32768       // global edge capacity (expected ~1100)
#define LDSE 8192        // in-LDS edge capacity for the UF kernel
#define IBCAP 256        // per-block in-band candidate capacity
#define BAND 2.0e-3f     // > bound ~9.8e-4 on |sim_exact - sim_fp16h| (unit rows)

typedef _Float16 f16x8  __attribute__((ext_vector_type(8)));
typedef float    f32x16 __attribute__((ext_vector_type(16)));

// ws layout: [0..64)  ctr: ctr[0]=edge count
//            [64..)   edges (CAP u32)
//            [1M..)   Vh    (4 MB fp16)

// ---------------------------------------------------------------------------
// Convert V fp32 -> fp16 high half (RTNE); block 0 zeroes the counter.
// ---------------------------------------------------------------------------
__global__ __launch_bounds__(256) void convert_kernel(
        const float* __restrict__ V, _Float16* __restrict__ Vh,
        unsigned* __restrict__ ctr) {
    if (blockIdx.x == 0 && threadIdx.x == 0) { ctr[0] = 0u; ctr[1] = 0u; }
    size_t t = (size_t)blockIdx.x * 256 + threadIdx.x;   // 262144 threads
    const float4* src = reinterpret_cast<const float4*>(V) + t * 2;
    float4 v0 = src[0], v1 = src[1];
    f16x8 h;
    h[0] = (_Float16)v0.x; h[1] = (_Float16)v0.y;
    h[2] = (_Float16)v0.z; h[3] = (_Float16)v0.w;
    h[4] = (_Float16)v1.x; h[5] = (_Float16)v1.y;
    h[6] = (_Float16)v1.z; h[7] = (_Float16)v1.w;
    *reinterpret_cast<f16x8*>(Vh + t * 8) = h;
}

__global__ void init_count(unsigned* ctr) {
    if (threadIdx.x == 0) { ctr[0] = 0u; ctr[1] = 0u; }
}

// ---------------------------------------------------------------------------
__device__ __forceinline__ void gload_lds16(const void* g, void* l) {
    __builtin_amdgcn_global_load_lds(
        (const __attribute__((address_space(1))) void*)g,
        (__attribute__((address_space(3))) void*)l, 16, 0, 0);
}

// ---------------------------------------------------------------------------
// h-only MFMA edge kernel v3 (LDS-BW-bound design).
// Tile 256(i) x 128(j), 256 threads = 4 waves (2x2), wave tile 128x64
// (4x2 of 32x32), v_mfma_f32_32x32x16_f16, KC=32 double-buffered:
//   LA[2][256x32] (16 KB ea) + LB[2][128x32] (8 KB ea) = 48 KB -> with
//   ~180 VGPR: 2 blocks/CU resident, grid 1056 over 512 slots (tail ~benign).
// LDS traffic = 1.125 KB/MFMA incl. stage-writes (v1 was 1.5) -> floor 7.7us.
// Row pitch 64 B => all ds accesses are <=2-way bank-aliased (free, m136):
// no swizzle; gload_lds dest strictly linear, global source strictly linear.
// Schedule (T3-minimal): STAGE(next) issued BEFORE COMPUTE(cur); single
// __syncthreads per K-iter both drains vmcnt and protects buffer reuse.
// Classification: sim >= thr+BAND -> sure edge; |sim-thr| < BAND -> deferred
// to in-block LDS list, re-resolved exactly in fp64 after acc regs die.
// C/D layout (m74/m101): col = lane&31, row = (reg&3)+8*(reg>>2)+4*(lane>>5);
// dual-operand same-k-map convention verified absmax=0 in rounds 3/5/6/7.
// ---------------------------------------------------------------------------
__global__ __launch_bounds__(256, 2) void edge_mfma(
        const _Float16* __restrict__ Vh,
        const float* __restrict__ V,
        const float* __restrict__ thr_p,
        unsigned* __restrict__ ctr,
        unsigned* __restrict__ edges) {
    // triangular decode over (bi: 32 row-tiles of 256, bj: 128-col tiles).
    // row bi holds bj in [2bi, 64); offset(bi) = bi*(65-bi); total 1056.
    int t = blockIdx.x;
    int bi = (int)((65.0f - sqrtf(4225.0f - 4.0f * (float)t)) * 0.5f);
    if (bi > 31) bi = 31;
    while (bi > 0 && bi * (65 - bi) > t) --bi;
    while ((bi + 1) * (64 - bi) <= t) ++bi;
    int bj = 2 * bi + (t - bi * (65 - bi));

    __shared__ _Float16 LA[2][256 * 32];       // 2 x 16 KB
    __shared__ _Float16 LB[2][128 * 32];       // 2 x  8 KB
    __shared__ unsigned ibl[IBCAP];            // in-band candidate keys
    __shared__ unsigned ibn;

    const float thr = thr_p[0];
    const float hi = thr + BAND, lo = thr - BAND;
    const int tid  = threadIdx.x;
    const int lane = tid & 63;
    const int wid  = tid >> 6;
    const int wr = wid >> 1, wc = wid & 1;     // 2x2 wave grid
    const int i0 = bi * 256, j0 = bj * 128;

    if (tid == 0) ibn = 0u;

    f32x16 acc[4][2];
#pragma unroll
    for (int a = 0; a < 4; ++a)
#pragma unroll
        for (int b = 0; b < 2; ++b) acc[a][b] = 0.0f;

    const int l31 = lane & 31, g = lane >> 5;
    const int srow = lane >> 2;                // staging row within instance
    const int sblk = lane & 3;                 // staging 16B block within row

    // ---- stage one KC=32 slice: A=16 + B=8 instances (1 KB each), 6/wave
    auto STAGE = [&](int buf, int kc) {
#pragma unroll
        for (int q = 0; q < 6; ++q) {
            const int qq = wid * 6 + q;        // 0..23
            if (qq < 16) {                     // A: 16 instances x 16 rows
                const int grow = i0 + qq * 16 + srow;
                gload_lds16(Vh + ((size_t)grow * DIM + kc + sblk * 8),
                            &LA[buf][qq * 512]);
            } else {                           // B: 8 instances x 16 rows
                const int ins = qq - 16;
                const int grow = j0 + ins * 16 + srow;
                gload_lds16(Vh + ((size_t)grow * DIM + kc + sblk * 8),
                            &LB[buf][ins * 512]);
            }
        }
    };

    // ---- compute one KC=32 slice from buf: 2 k-steps x 8 MFMA ----
    auto COMPUTE = [&](int buf) {
#pragma unroll
        for (int s = 0; s < 2; ++s) {
            const int xo = s * 16 + g * 8;     // half-offset within row
            f16x8 af[4], bf[2];
#pragma unroll
            for (int a = 0; a < 4; ++a)
                af[a] = *(const f16x8*)&LA[buf][(wr * 128 + a * 32 + l31) * 32 + xo];
#pragma unroll
            for (int b = 0; b < 2; ++b)
                bf[b] = *(const f16x8*)&LB[buf][(wc * 64 + b * 32 + l31) * 32 + xo];
#pragma unroll
            for (int a = 0; a < 4; ++a)
#pragma unroll
                for (int b = 0; b < 2; ++b)
                    acc[a][b] = __builtin_amdgcn_mfma_f32_32x32x16_f16(
                        af[a], bf[b], acc[a][b], 0, 0, 0);
        }
    };

    STAGE(0, 0);
    __syncthreads();
#pragma unroll
    for (int it = 0; it < 8; ++it) {
        if (it < 7) STAGE((it + 1) & 1, (it + 1) * 32);
        COMPUTE(it & 1);
        __syncthreads();   // drains vmcnt (next buf ready) + read-before-write
    }

    // ---- epilogue pass 1: classify; sure edges emit, in-band defer ----
#pragma unroll
    for (int a = 0; a < 4; ++a)
#pragma unroll
        for (int b = 0; b < 2; ++b)
#pragma unroll
            for (int reg = 0; reg < 16; ++reg) {
                float sim = acc[a][b][reg];
                int rr = (reg & 3) + 8 * (reg >> 2) + 4 * g;
                int i = i0 + wr * 128 + a * 32 + rr;
                int j = j0 + wc * 64 + b * 32 + l31;
                if (j > i && sim >= lo) {
                    unsigned key = ((unsigned)i << 13) | (unsigned)j;
                    if (sim >= hi) {
                        unsigned p = atomicAdd(&ctr[0], 1u);
                        if (p < CAP) edges[p] = key;
                    } else {
                        unsigned p = atomicAdd(&ibn, 1u);
                        if (p < IBCAP) ibl[p] = key;
                    }
                }
            }
    __syncthreads();

    // ---- epilogue pass 2: exact fp64 re-resolution (acc regs dead) ----
    unsigned nib = ibn; if (nib > IBCAP) nib = IBCAP;
    const double thrd = (double)thr;
    for (unsigned q = tid; q < nib; q += 256) {
        unsigned key = ibl[q];
        int i = (int)(key >> 13), j = (int)(key & 8191u);
        const float4* a4 = reinterpret_cast<const float4*>(V + (size_t)i * DIM);
        const float4* b4 = reinterpret_cast<const float4*>(V + (size_t)j * DIM);
        double s = 0.0;
#pragma unroll 4
        for (int k = 0; k < DIM / 4; ++k) {
            float4 x = a4[k], y = b4[k];
            s += (double)x.x * y.x + (double)x.y * y.y
               + (double)x.z * y.z + (double)x.w * y.w;
        }
        if (s >= thrd) {
            unsigned p = atomicAdd(&ctr[0], 1u);
            if (p < CAP) edges[p] = key;
        }
    }
}

// ---------------------------------------------------------------------------
// fp32 fallback (exact path, no band) if ws is too small for Vh.
// ---------------------------------------------------------------------------
__global__ __launch_bounds__(256) void edge_kernel(
        const float* __restrict__ V,
        const float* __restrict__ thr_p,
        unsigned*    __restrict__ ctr,
        unsigned*    __restrict__ edges) {
    const int bi = blockIdx.y, bj = blockIdx.x;
    if (bj < bi) return;

    __shared__ float As[128 * 32];
    __shared__ float Bs[128 * 32];

    const float thr = thr_p[0];
    const int tid = threadIdx.x;
    const int tx = tid & 15, ty = tid >> 4;
    const int i0 = bi * 128, j0 = bj * 128;

    float acc[8][8];
#pragma unroll
    for (int r = 0; r < 8; ++r)
#pragma unroll
        for (int c = 0; c < 8; ++c) acc[r][c] = 0.f;

    const int srow = tid >> 3, sq = tid & 7;

    for (int kc = 0; kc < DIM; kc += 32) {
#pragma unroll
        for (int p = 0; p < 4; ++p) {
            int row = srow + 32 * p;
            float4 va = *reinterpret_cast<const float4*>(
                &V[(size_t)(i0 + row) * DIM + kc + sq * 4]);
            float4 vb = *reinterpret_cast<const float4*>(
                &V[(size_t)(j0 + row) * DIM + kc + sq * 4]);
            int w = row * 32 + ((sq ^ ((row >> 3) & 7)) << 2);
            *reinterpret_cast<float4*>(&As[w]) = va;
            *reinterpret_cast<float4*>(&Bs[w]) = vb;
        }
        __syncthreads();
#pragma unroll
        for (int k4 = 0; k4 < 8; ++k4) {
            const float* pA = &As[(ty * 8) * 32 + ((k4 ^ (ty & 7)) << 2)];
            const float* pB = &Bs[(tx * 8) * 32 + ((k4 ^ (tx & 7)) << 2)];
            float4 a[8], b[8];
#pragma unroll
            for (int r = 0; r < 8; ++r)
                a[r] = *reinterpret_cast<const float4*>(&pA[r * 32]);
#pragma unroll
            for (int c = 0; c < 8; ++c)
                b[c] = *reinterpret_cast<const float4*>(&pB[c * 32]);
#pragma unroll
            for (int r = 0; r < 8; ++r)
#pragma unroll
                for (int c = 0; c < 8; ++c) {
                    acc[r][c] = fmaf(a[r].x, b[c].x, acc[r][c]);
                    acc[r][c] = fmaf(a[r].y, b[c].y, acc[r][c]);
                    acc[r][c] = fmaf(a[r].z, b[c].z, acc[r][c]);
                    acc[r][c] = fmaf(a[r].w, b[c].w, acc[r][c]);
                }
        }
        __syncthreads();
    }
#pragma unroll
    for (int r = 0; r < 8; ++r)
#pragma unroll
        for (int c = 0; c < 8; ++c) {
            int i = i0 + ty * 8 + r;
            int j = j0 + tx * 8 + c;
            if (j > i && acc[r][c] >= thr) {
                unsigned p = atomicAdd(&ctr[0], 1u);
                if (p < CAP) edges[p] = ((unsigned)i << 13) | (unsigned)j;
            }
        }
}

// ---------------------------------------------------------------------------
// UF kernel (one block, 1024 threads): parallel winner-rounds exact replay
// of the sequential merge, then parallel root write-out.
//
// Winner-rounds correctness: per round each live edge e computes its current
// roots (ri,rj) and atomicMin's its packed key (= sequential order index)
// into S[ri], S[rj].  e applies iff it holds both slots.  (a) Every live
// edge f<e is then root-disjoint from e; disjoint unions commute, so e's
// state restricted to its roots equals its sequential state -> par[rj]=ri
// is the exact sequential effect.  (b) Winner root-sets are pairwise
// disjoint (shared root => equal slot value => equal key; keys unique), so
// parallel application + root-preserving compression is race-free, and
// concurrent phase-B finds cannot produce a false win.  (c) The globally
// smallest live key always wins -> >=1 retire/round.
// Ping-pong slot arrays: phase B clears the OTHER array, so each round has
// exactly 2 barriers (the second fused into __syncthreads_count liveness).
// ---------------------------------------------------------------------------
__global__ __launch_bounds__(1024) void uf_kernel(
        const unsigned* __restrict__ ctr,
        const unsigned* __restrict__ edges,
        int* __restrict__ out) {
    __shared__ int      par[NPTS];        // 32 KB
    __shared__ unsigned slotA[NPTS];      // 32 KB
    __shared__ unsigned slotB[NPTS];      // 32 KB
    __shared__ unsigned sedge[LDSE];      // 32 KB

    const int tid = threadIdx.x;

    unsigned EC = ctr[0]; if (EC > LDSE) EC = LDSE;

    for (int t = tid; t < NPTS; t += 1024) {
        par[t] = t; slotA[t] = 0xFFFFFFFFu; slotB[t] = 0xFFFFFFFFu;
    }
    for (unsigned e = tid; e < EC; e += 1024) sedge[e] = edges[e];
    __syncthreads();

    volatile int* vpar = par;

    for (int round = 0;; ++round) {
        unsigned* S = (round & 1) ? slotB : slotA;
        unsigned* T = (round & 1) ? slotA : slotB;

        // Phase A: finds against round-start state + slot bids
        for (unsigned e = tid; e < EC; e += 1024) {
            unsigned key = sedge[e];
            if (key & 0x80000000u) continue;
            int ri = (int)(key >> 13), rj = (int)(key & 8191u);
            int p;
            while ((p = vpar[ri]) != ri) ri = p;
            while ((p = vpar[rj]) != rj) rj = p;
            atomicMin(&S[ri], key);
            atomicMin(&S[rj], key);
        }
        __syncthreads();

        // Phase B: winners apply; clear other slot array; track liveness
        int mylive = 0;
        for (unsigned e = tid; e < EC; e += 1024) {
            unsigned key = sedge[e];
            if (key & 0x80000000u) continue;
            int i = (int)(key >> 13), j = (int)(key & 8191u);
            int ri = i, rj = j, p;
            while ((p = vpar[ri]) != ri) ri = p;
            while ((p = vpar[rj]) != rj) rj = p;
            if (S[ri] == key && S[rj] == key) {
                if (ri != rj) { par[rj] = ri; par[i] = ri; par[j] = ri; }
                sedge[e] = key | 0x80000000u;
            } else {
                mylive = 1;
            }
        }
        for (int t = tid; t < NPTS; t += 1024) T[t] = 0xFFFFFFFFu;
        if (__syncthreads_count(mylive) == 0) break;
    }

    // ---- root write-out ----
    for (int t = tid; t < NPTS; t += 1024) {
        int r = t, p;
        while ((p = par[r]) != r) r = p;
        out[t] = r;
    }
}

extern "C" void kernel_launch(void* const* d_in, const int* in_sizes, int n_in,
                              void* d_out, int out_size, void* d_ws, size_t ws_size,
                              hipStream_t stream) {
    const float* V     = (const float*)d_in[0];
    const float* thr_p = (const float*)d_in[1];
    // d_in[2] (batch_size) provably does not affect the result.

    unsigned* ctr   = (unsigned*)d_ws;
    unsigned* edges = (unsigned*)((char*)d_ws + 64);
    int*      out   = (int*)d_out;

    const size_t vhOff = 1u << 20;
    const size_t vN    = (size_t)NPTS * DIM;
    const size_t need  = vhOff + vN * sizeof(_Float16) + 65536;

    if (ws_size >= need) {
        _Float16* Vh = (_Float16*)((char*)d_ws + vhOff);
        hipLaunchKernelGGL(convert_kernel, dim3(1024), dim3(256), 0, stream,
                           V, Vh, ctr);
        hipLaunchKernelGGL(edge_mfma, dim3(1056), dim3(256), 0, stream,
                           Vh, V, thr_p, ctr, edges);
    } else {
        hipLaunchKernelGGL(init_count, dim3(1), dim3(64), 0, stream, ctr);
        hipLaunchKernelGGL(edge_kernel, dim3(64, 64), dim3(256), 0, stream,
                           V, thr_p, ctr, edges);
    }
    hipLaunchKernelGGL(uf_kernel, dim3(1), dim3(1024), 0, stream,
                       ctr, edges, out);
}